// Round 6
// baseline (191.609 us; speedup 1.0000x reference)
//
#include <hip/hip_runtime.h>
#include <math.h>

#define B 8
#define D 256
#define N_LIVE 10000
#define K_NEW 32
#define KC 10032
#define NS 100
#define NROW 101            // 100 bootstrap rows + 1 plain-softmax row (the score)
#define EPS 0.1f
#define CAP 1024            // active-set capacity (expected ~75 per b)
#define ACT_CUT 87.0f       // exp(-87)=1.65e-38: below fp32-normal -> weight 0 anyway
#define LBLK 314            // k_logits blocks per b (32 particles each; last partial)
#define BMAX_STRIDE 320

// ---- workspace layout in floats ----
// hdr: M[b] at stride 16 (line-padded) + act_cnt[8] at [128..135]
#define WS_HDR    0                            // 160 ints
#define WS_BMAX   160                          // B*320 floats: per-block maxima
#define WS_LOGITS (WS_BMAX + B * BMAX_STRIDE)  // B*KC floats
#define WS_ACTE   (WS_LOGITS + B * KC)         // B*CAP floats: e_j = exp(l-M)
#define WS_ACTI   (WS_ACTE + B * CAP)          // B*CAP ints: particle index j
#define WS_LUT    (WS_ACTI + B * CAP)          // B*KC ushorts = B*KC/2 floats
#define WS_BOOT   (WS_LUT + B * KC / 2)        // B*NROW*D floats   (~1.4 MB total)

// ---------------- kernel 1: logits[b,k] + per-block max ----------------
// 8 particles per wave (32/block): 8 independent 1KB row loads in flight,
// 8 interleaved shuffle-reduce chains. No global atomics (r4 lesson).
// KC%8==0 -> a wave's 8 particles are fully valid or fully out-of-range.
__global__ __launch_bounds__(256) void k_logits(
    const float* __restrict__ xt, const float* __restrict__ live_x0,
    const float* __restrict__ live_ll, const float* __restrict__ x0n,
    const float* __restrict__ lln, const float* __restrict__ ts_p,
    float* __restrict__ logits, float* __restrict__ bmax) {
  int b = blockIdx.y;
  int w = threadIdx.x >> 6;
  int lane = threadIdx.x & 63;
  int k0 = blockIdx.x * 32 + w * 8;
  bool valid = (k0 < KC);
  int kb = valid ? k0 : 0;                 // safe dup loads for the 2 dead waves
  float4 c = ((const float4*)(xt + b * D))[lane];

  float s[8];
#pragma unroll
  for (int p = 0; p < 8; p++) {
    int k = kb + p;
    const float* src = (k < N_LIVE)
        ? (live_x0 + ((size_t)b * N_LIVE + k) * D)
        : (x0n + ((size_t)b * K_NEW + (k - N_LIVE)) * D);
    float4 v = ((const float4*)src)[lane];
    float dx = v.x - c.x, dy = v.y - c.y, dz = v.z - c.z, dw = v.w - c.w;
    s[p] = dx * dx + dy * dy + dz * dz + dw * dw;
  }
#pragma unroll
  for (int off = 32; off; off >>= 1) {     // 8 interleaved chains hide DS latency
#pragma unroll
    for (int p = 0; p < 8; p++) s[p] += __shfl_xor(s[p], off);
  }
  __shared__ float wlog[4];
  if (lane == 0) {
    float ts = *ts_p;
    float inv2 = 0.5f / (ts * ts), lts = logf(ts);
    float o[8];
#pragma unroll
    for (int p = 0; p < 8; p++) {
      int k = kb + p;
      o[p] = (k < N_LIVE)
          ? live_ll[(size_t)b * N_LIVE + k] - s[p] * inv2 - lts
          : lln[(size_t)b * K_NEW + (k - N_LIVE)];   // gaussian corr cancels exactly
    }
    if (valid) {
      float4 o0 = {o[0], o[1], o[2], o[3]}, o1 = {o[4], o[5], o[6], o[7]};
      *(float4*)(logits + (size_t)b * KC + kb) = o0;
      *(float4*)(logits + (size_t)b * KC + kb + 4) = o1;
      float m = fmaxf(fmaxf(fmaxf(o[0], o[1]), fmaxf(o[2], o[3])),
                      fmaxf(fmaxf(o[4], o[5]), fmaxf(o[6], o[7])));
      wlog[w] = m;
    } else {
      wlog[w] = -INFINITY;
    }
  }
  __syncthreads();
  if (threadIdx.x == 0)
    bmax[b * BMAX_STRIDE + blockIdx.x] =
        fmaxf(fmaxf(wlog[0], wlog[1]), fmaxf(wlog[2], wlog[3]));
}

// ---------------- kernel 1b: reduce per-block maxima -> M[b] ----------------
__global__ __launch_bounds__(256) void k_bmax(
    const float* __restrict__ bmax, float* __restrict__ hdr) {
  int b = blockIdx.x;
  int tid = threadIdx.x;
  float m = -INFINITY;
  for (int i = tid; i < LBLK; i += 256) m = fmaxf(m, bmax[b * BMAX_STRIDE + i]);
#pragma unroll
  for (int off = 32; off; off >>= 1) m = fmaxf(m, __shfl_xor(m, off));
  __shared__ float sm[4];
  if ((tid & 63) == 0) sm[tid >> 6] = m;
  __syncthreads();
  if (tid == 0)
    hdr[b * 16] = fmaxf(fmaxf(sm[0], sm[1]), fmaxf(sm[2], sm[3]));  // plain store
}

// ---------------- kernel 2: active-set selection ----------------
// Active = logit within ACT_CUT of the per-b max; everything else has
// exp(l-M) below fp32-normal range -> weight 0 in fp32. ~75 actives per b.
__global__ __launch_bounds__(256) void k_select(
    const float* __restrict__ logits, const float* __restrict__ hdrM,
    unsigned* __restrict__ hdr, float* __restrict__ act_e,
    int* __restrict__ act_idx, unsigned short* __restrict__ lut) {
  int b = blockIdx.y;
  int tid = blockIdx.x * 256 + threadIdx.x;   // 8 blocks per b
  float M = hdrM[b * 16];
  const float* lg = logits + (size_t)b * KC;
  int* cnt = (int*)&hdr[128 + b];
  for (int k = tid; k < KC; k += 8 * 256) {
    float l = lg[k];
    unsigned short v = 0;
    if (l > M - ACT_CUT) {
      int pos = atomicAdd(cnt, 1);            // rare: ~75 per b total
      if (pos < CAP) {
        act_e[b * CAP + pos] = expf(l - M);
        act_idx[b * CAP + pos] = k;
        v = (unsigned short)(pos + 1);
      }
    }
    lut[(size_t)b * KC + k] = v;
  }
}

// ---------------- kernel 3: fused count + sparse weighted sum ----------------
// One block per (n,b). Counting: uint16 lut (20KB/b, L1/L2-hot), LDS atomics
// only on ~75 hits per 10032 draws. Weighted sum: lane covers d via float4
// (64 lanes x 16B = full row), the 4 waves split the nnz rows 4-ways with
// 2-way unroll (~7 latency steps vs 55), LDS partial-combine at the end.
// n==100 is the identity row (plain softmax -> final score).
__global__ __launch_bounds__(256) void k_boot(
    const float* __restrict__ live_x0, const float* __restrict__ x0n,
    const float* __restrict__ act_e, const int* __restrict__ act_idx,
    const unsigned* __restrict__ hdr, const unsigned short* __restrict__ lut,
    const int* __restrict__ boot_idx, float* __restrict__ boot) {
  int n = blockIdx.x;   // 0..100
  int b = blockIdx.y;
  int tid = threadIdx.x;
  int nw = tid >> 6, lane = tid & 63;
  __shared__ int cnt[CAP];
  __shared__ float wval[CAP];
  __shared__ int widx[CAP];
  __shared__ float4 part[4][64];
  __shared__ int snnz;
  __shared__ float sden[4];
  int A = min((int)hdr[128 + b], CAP);
  for (int i = tid; i < A; i += 256) cnt[i] = 0;
  if (tid == 0) snnz = 0;
  __syncthreads();

  if (n < NS) {
    const int4* row = (const int4*)(boot_idx + ((size_t)n * B + b) * KC);
    const unsigned short* lutb = lut + (size_t)b * KC;
    for (int k = tid; k < KC / 4; k += 256) {   // KC%4==0
      int4 v = row[k];
      int t;
      t = lutb[v.x]; if (t) atomicAdd(&cnt[t - 1], 1);
      t = lutb[v.y]; if (t) atomicAdd(&cnt[t - 1], 1);
      t = lutb[v.z]; if (t) atomicAdd(&cnt[t - 1], 1);
      t = lutb[v.w]; if (t) atomicAdd(&cnt[t - 1], 1);
    }
  } else {
    for (int i = tid; i < A; i += 256) cnt[i] = 1;
  }
  __syncthreads();

  // compact nonzero actives + denominator
  float dpart = 0.f;
  for (int i = tid; i < A; i += 256) {
    int c = cnt[i];
    if (c) {
      float w = (float)c * act_e[b * CAP + i];
      int pos = atomicAdd(&snnz, 1);
      wval[pos] = w;
      widx[pos] = act_idx[b * CAP + i];
      dpart += w;
    }
  }
#pragma unroll
  for (int off = 32; off; off >>= 1) dpart += __shfl_xor(dpart, off);
  if ((tid & 63) == 0) sden[tid >> 6] = dpart;
  __syncthreads();
  float inv = 1.f / (sden[0] + sden[1] + sden[2] + sden[3]);
  int nnz = snnz;

  const float* lx = live_x0 + (size_t)b * N_LIVE * D;
  const float* nx = x0n + (size_t)b * K_NEW * D;
  float4 a0 = {0.f, 0.f, 0.f, 0.f}, a1 = {0.f, 0.f, 0.f, 0.f};
  int p = nw;
  for (; p + 4 < nnz; p += 8) {          // 2 independent rows in flight per wave
    int j0 = widx[p], j1 = widx[p + 4];
    float w0 = wval[p], w1 = wval[p + 4];
    const float4* r0 = (const float4*)((j0 < N_LIVE) ? (lx + (size_t)j0 * D)
                                                     : (nx + (size_t)(j0 - N_LIVE) * D));
    const float4* r1 = (const float4*)((j1 < N_LIVE) ? (lx + (size_t)j1 * D)
                                                     : (nx + (size_t)(j1 - N_LIVE) * D));
    float4 v0 = r0[lane], v1 = r1[lane];
    a0.x = fmaf(w0, v0.x, a0.x); a0.y = fmaf(w0, v0.y, a0.y);
    a0.z = fmaf(w0, v0.z, a0.z); a0.w = fmaf(w0, v0.w, a0.w);
    a1.x = fmaf(w1, v1.x, a1.x); a1.y = fmaf(w1, v1.y, a1.y);
    a1.z = fmaf(w1, v1.z, a1.z); a1.w = fmaf(w1, v1.w, a1.w);
  }
  if (p < nnz) {
    int j = widx[p];
    float w = wval[p];
    const float4* r = (const float4*)((j < N_LIVE) ? (lx + (size_t)j * D)
                                                   : (nx + (size_t)(j - N_LIVE) * D));
    float4 v = r[lane];
    a0.x = fmaf(w, v.x, a0.x); a0.y = fmaf(w, v.y, a0.y);
    a0.z = fmaf(w, v.z, a0.z); a0.w = fmaf(w, v.w, a0.w);
  }
  a0.x += a1.x; a0.y += a1.y; a0.z += a1.z; a0.w += a1.w;
  part[nw][lane] = a0;
  __syncthreads();
  if (nw == 0) {
    float4 q0 = part[0][lane], q1 = part[1][lane], q2 = part[2][lane], q3 = part[3][lane];
    float4 r;
    r.x = ((q0.x + q1.x) + (q2.x + q3.x)) * inv;
    r.y = ((q0.y + q1.y) + (q2.y + q3.y)) * inv;
    r.z = ((q0.z + q1.z) + (q2.z + q3.z)) * inv;
    r.w = ((q0.w + q1.w) + (q2.w + q3.w)) * inv;
    ((float4*)(boot + ((size_t)b * NROW + n) * D))[lane] = r;
  }
}

// ---------------- kernel 4: std over bootstrap rows + epilogue ----------------
__global__ __launch_bounds__(256) void k_final(
    const float* __restrict__ boot, const float* __restrict__ xt,
    const float* __restrict__ ts_p, float* __restrict__ out) {
  int b = blockIdx.x;
  int d = threadIdx.x;
  float ts = *ts_p;
  const float* bb = boot + (size_t)b * NROW * D + d;
  float sum = 0.f;
#pragma unroll 4
  for (int n = 0; n < NS; n++) sum += bb[(size_t)n * D];
  float mean = sum / (float)NS;
  float vs = 0.f;
#pragma unroll 4
  for (int n = 0; n < NS; n++) { float t = bb[(size_t)n * D] - mean; vs += t * t; }
  float sigma_raw = sqrtf(vs / (float)(NS - 1));
  // std((x - xt)/ts) = std(x)/ts   (ts > 0); condition: sigma_v < EPS*ts
  bool ok = (sigma_raw / ts) < (EPS * ts);
  // score = (sum_k w*x - xt)/ts  since sum_k w == 1
  out[(size_t)b * D + d] = (bb[(size_t)NS * D] - xt[(size_t)b * D + d]) / ts;
  unsigned long long m = __ballot(ok);
  __shared__ int wok[4];
  if ((d & 63) == 0) wok[d >> 6] = (m == 0xFFFFFFFFFFFFFFFFull) ? 1 : 0;
  __syncthreads();
  if (d == 0) out[(size_t)B * D + b] = (wok[0] & wok[1] & wok[2] & wok[3]) ? 1.0f : 0.0f;
}

extern "C" void kernel_launch(void* const* d_in, const int* in_sizes, int n_in,
                              void* d_out, int out_size, void* d_ws, size_t ws_size,
                              hipStream_t stream) {
  const float* xt       = (const float*)d_in[0];
  const float* live_x0  = (const float*)d_in[1];
  const float* live_ll  = (const float*)d_in[2];
  const float* x0n      = (const float*)d_in[3];
  const float* lln      = (const float*)d_in[4];
  const float* ts_p     = (const float*)d_in[5];
  const int*   boot_idx = (const int*)d_in[6];
  float* out = (float*)d_out;
  float* ws  = (float*)d_ws;

  float* hdrM              = ws + WS_HDR;
  unsigned* hdr            = (unsigned*)(ws + WS_HDR);
  float* bmax              = ws + WS_BMAX;
  float* logits            = ws + WS_LOGITS;
  float* act_e             = ws + WS_ACTE;
  int*   act_idx           = (int*)(ws + WS_ACTI);
  unsigned short* lut      = (unsigned short*)(ws + WS_LUT);
  float* boot              = ws + WS_BOOT;

  // zero header (act_cnt counters; M[b] overwritten by k_bmax anyway)
  hipMemsetAsync(hdr, 0, 160 * sizeof(unsigned), stream);

  k_logits<<<dim3(LBLK, B), 256, 0, stream>>>(xt, live_x0, live_ll, x0n, lln, ts_p, logits, bmax);
  k_bmax<<<dim3(B), 256, 0, stream>>>(bmax, hdrM);
  k_select<<<dim3(8, B), 256, 0, stream>>>(logits, hdrM, hdr, act_e, act_idx, lut);
  k_boot<<<dim3(NROW, B), 256, 0, stream>>>(live_x0, x0n, act_e, act_idx, hdr, lut, boot_idx, boot);
  k_final<<<dim3(B), 256, 0, stream>>>(boot, xt, ts_p, out);
}

// Round 7
// 171.654 us; speedup vs baseline: 1.1163x; 1.1163x over previous
//
#include <hip/hip_runtime.h>
#include <math.h>

#define B 8
#define D 256
#define N_LIVE 10000
#define K_NEW 32
#define KC 10032
#define NS 100
#define NROW 101            // 100 bootstrap rows + 1 plain-softmax row (the score)
#define EPS 0.1f
#define CAP 1024            // active-set capacity (expected ~75 per b)
#define ACT_CUT 87.0f       // exp(-87)=1.65e-38: below fp32-normal -> weight 0 anyway
#define LBLK 314            // k_logits blocks per b (32 particles each; last partial)
#define BMAX_STRIDE 320

// ---- workspace layout in floats ----
// hdr: act_cnt[8] at [128..135] (slots 0..127 unused, kept for layout stability)
#define WS_HDR    0                            // 160 ints
#define WS_BMAX   160                          // B*320 floats: per-block maxima
#define WS_LOGITS (WS_BMAX + B * BMAX_STRIDE)  // B*KC floats
#define WS_ACTE   (WS_LOGITS + B * KC)         // B*CAP floats: e_j = exp(l-M)
#define WS_ACTI   (WS_ACTE + B * CAP)          // B*CAP ints: particle index j
#define WS_LUT    (WS_ACTI + B * CAP)          // B*KC ushorts = B*KC/2 floats
#define WS_BOOT   (WS_LUT + B * KC / 2)        // B*NROW*D floats   (~1.4 MB total)

// ---------------- kernel 1: logits[b,k] + per-block max ----------------
// 8 particles per wave (32/block): 8 independent 1KB row loads in flight,
// 8 interleaved shuffle-reduce chains. No global atomics (r4 lesson: 20k
// atomicMax onto 8 lines serialized ~50us). Block (0,b) also zeroes the
// act_cnt counter (replaces the hipMemsetAsync dispatch).
__global__ __launch_bounds__(256) void k_logits(
    const float* __restrict__ xt, const float* __restrict__ live_x0,
    const float* __restrict__ live_ll, const float* __restrict__ x0n,
    const float* __restrict__ lln, const float* __restrict__ ts_p,
    float* __restrict__ logits, float* __restrict__ bmax,
    unsigned* __restrict__ hdr) {
  int b = blockIdx.y;
  if (blockIdx.x == 0 && threadIdx.x == 0) hdr[128 + b] = 0;  // act_cnt := 0
  int w = threadIdx.x >> 6;
  int lane = threadIdx.x & 63;
  int k0 = blockIdx.x * 32 + w * 8;
  bool valid = (k0 < KC);
  int kb = valid ? k0 : 0;                 // safe dup loads for the dead waves
  float4 c = ((const float4*)(xt + b * D))[lane];

  float s[8];
#pragma unroll
  for (int p = 0; p < 8; p++) {
    int k = kb + p;
    const float* src = (k < N_LIVE)
        ? (live_x0 + ((size_t)b * N_LIVE + k) * D)
        : (x0n + ((size_t)b * K_NEW + (k - N_LIVE)) * D);
    float4 v = ((const float4*)src)[lane];
    float dx = v.x - c.x, dy = v.y - c.y, dz = v.z - c.z, dw = v.w - c.w;
    s[p] = dx * dx + dy * dy + dz * dz + dw * dw;
  }
#pragma unroll
  for (int off = 32; off; off >>= 1) {     // 8 interleaved chains hide DS latency
#pragma unroll
    for (int p = 0; p < 8; p++) s[p] += __shfl_xor(s[p], off);
  }
  __shared__ float wlog[4];
  if (lane == 0) {
    float ts = *ts_p;
    float inv2 = 0.5f / (ts * ts), lts = logf(ts);
    float o[8];
#pragma unroll
    for (int p = 0; p < 8; p++) {
      int k = kb + p;
      o[p] = (k < N_LIVE)
          ? live_ll[(size_t)b * N_LIVE + k] - s[p] * inv2 - lts
          : lln[(size_t)b * K_NEW + (k - N_LIVE)];   // gaussian corr cancels exactly
    }
    if (valid) {
      float4 o0 = {o[0], o[1], o[2], o[3]}, o1 = {o[4], o[5], o[6], o[7]};
      *(float4*)(logits + (size_t)b * KC + kb) = o0;
      *(float4*)(logits + (size_t)b * KC + kb + 4) = o1;
      wlog[w] = fmaxf(fmaxf(fmaxf(o[0], o[1]), fmaxf(o[2], o[3])),
                      fmaxf(fmaxf(o[4], o[5]), fmaxf(o[6], o[7])));
    } else {
      wlog[w] = -INFINITY;
    }
  }
  __syncthreads();
  if (threadIdx.x == 0)
    bmax[b * BMAX_STRIDE + blockIdx.x] =
        fmaxf(fmaxf(wlog[0], wlog[1]), fmaxf(wlog[2], wlog[3]));
}

// ---------------- kernel 2: max-reduce + active-set selection (fused) ----------------
// 8 blocks per b; each block redundantly reduces the 314 per-block maxima
// (trivial) then selects. Active = logit within ACT_CUT of the per-b max;
// everything else has exp(l-M) below fp32-normal range -> weight 0 in fp32.
__global__ __launch_bounds__(256) void k_select(
    const float* __restrict__ logits, const float* __restrict__ bmax,
    unsigned* __restrict__ hdr, float* __restrict__ act_e,
    int* __restrict__ act_idx, unsigned short* __restrict__ lut) {
  int b = blockIdx.y;
  __shared__ float sm[4];
  float m = -INFINITY;
  for (int i = threadIdx.x; i < LBLK; i += 256)
    m = fmaxf(m, bmax[b * BMAX_STRIDE + i]);
#pragma unroll
  for (int off = 32; off; off >>= 1) m = fmaxf(m, __shfl_xor(m, off));
  if ((threadIdx.x & 63) == 0) sm[threadIdx.x >> 6] = m;
  __syncthreads();
  float M = fmaxf(fmaxf(sm[0], sm[1]), fmaxf(sm[2], sm[3]));

  int tid = blockIdx.x * 256 + threadIdx.x;
  const float* lg = logits + (size_t)b * KC;
  int* cnt = (int*)&hdr[128 + b];
  for (int k = tid; k < KC; k += 8 * 256) {
    float l = lg[k];
    unsigned short v = 0;
    if (l > M - ACT_CUT) {
      int pos = atomicAdd(cnt, 1);            // rare: ~75 per b total
      if (pos < CAP) {
        act_e[b * CAP + pos] = expf(l - M);
        act_idx[b * CAP + pos] = k;
        v = (unsigned short)(pos + 1);
      }
    }
    lut[(size_t)b * KC + k] = v;
  }
}

// ---------------- kernel 3: fused count + sparse weighted sum ----------------
// One block per (n,b). The 20KB uint16 lut is staged into LDS so the 10032
// random lookups per block are ds_read_u16 (2-way conflicts free) instead of
// L1 line-serialized gathers. LDS atomics only on ~75 hits. Weighted sum:
// lane covers d via float4 (64 lanes x 16B = full row), 4 waves split the
// nnz rows 4-ways with 2-way unroll, LDS partial-combine at the end.
// n==100 is the identity row (plain softmax -> final score).
__global__ __launch_bounds__(256) void k_boot(
    const float* __restrict__ live_x0, const float* __restrict__ x0n,
    const float* __restrict__ act_e, const int* __restrict__ act_idx,
    const unsigned* __restrict__ hdr, const unsigned short* __restrict__ lut,
    const int* __restrict__ boot_idx, float* __restrict__ boot) {
  int n = blockIdx.x;   // 0..100
  int b = blockIdx.y;
  int tid = threadIdx.x;
  int nw = tid >> 6, lane = tid & 63;
  __shared__ unsigned short slut[KC];   // 20064 B
  __shared__ int cnt[CAP];
  __shared__ float wval[CAP];
  __shared__ int widx[CAP];
  __shared__ float4 part[4][64];
  __shared__ int snnz;
  __shared__ float sden[4];
  int A = min((int)hdr[128 + b], CAP);
  for (int i = tid; i < A; i += 256) cnt[i] = 0;
  if (tid == 0) snnz = 0;
  if (n < NS) {                         // stage lut -> LDS (coalesced u32 copy)
    const unsigned* src = (const unsigned*)(lut + (size_t)b * KC);
    unsigned* dst = (unsigned*)slut;
    for (int i = tid; i < KC / 2; i += 256) dst[i] = src[i];
  }
  __syncthreads();

  if (n < NS) {
    const int4* row = (const int4*)(boot_idx + ((size_t)n * B + b) * KC);
    for (int k = tid; k < KC / 4; k += 256) {   // KC%4==0
      int4 v = row[k];
      int t;
      t = slut[v.x]; if (t) atomicAdd(&cnt[t - 1], 1);
      t = slut[v.y]; if (t) atomicAdd(&cnt[t - 1], 1);
      t = slut[v.z]; if (t) atomicAdd(&cnt[t - 1], 1);
      t = slut[v.w]; if (t) atomicAdd(&cnt[t - 1], 1);
    }
  } else {
    for (int i = tid; i < A; i += 256) cnt[i] = 1;
  }
  __syncthreads();

  // compact nonzero actives + denominator
  float dpart = 0.f;
  for (int i = tid; i < A; i += 256) {
    int c = cnt[i];
    if (c) {
      float w = (float)c * act_e[b * CAP + i];
      int pos = atomicAdd(&snnz, 1);
      wval[pos] = w;
      widx[pos] = act_idx[b * CAP + i];
      dpart += w;
    }
  }
#pragma unroll
  for (int off = 32; off; off >>= 1) dpart += __shfl_xor(dpart, off);
  if ((tid & 63) == 0) sden[tid >> 6] = dpart;
  __syncthreads();
  float inv = 1.f / (sden[0] + sden[1] + sden[2] + sden[3]);
  int nnz = snnz;

  const float* lx = live_x0 + (size_t)b * N_LIVE * D;
  const float* nx = x0n + (size_t)b * K_NEW * D;
  float4 a0 = {0.f, 0.f, 0.f, 0.f}, a1 = {0.f, 0.f, 0.f, 0.f};
  int p = nw;
  for (; p + 4 < nnz; p += 8) {          // 2 independent rows in flight per wave
    int j0 = widx[p], j1 = widx[p + 4];
    float w0 = wval[p], w1 = wval[p + 4];
    const float4* r0 = (const float4*)((j0 < N_LIVE) ? (lx + (size_t)j0 * D)
                                                     : (nx + (size_t)(j0 - N_LIVE) * D));
    const float4* r1 = (const float4*)((j1 < N_LIVE) ? (lx + (size_t)j1 * D)
                                                     : (nx + (size_t)(j1 - N_LIVE) * D));
    float4 v0 = r0[lane], v1 = r1[lane];
    a0.x = fmaf(w0, v0.x, a0.x); a0.y = fmaf(w0, v0.y, a0.y);
    a0.z = fmaf(w0, v0.z, a0.z); a0.w = fmaf(w0, v0.w, a0.w);
    a1.x = fmaf(w1, v1.x, a1.x); a1.y = fmaf(w1, v1.y, a1.y);
    a1.z = fmaf(w1, v1.z, a1.z); a1.w = fmaf(w1, v1.w, a1.w);
  }
  if (p < nnz) {
    int j = widx[p];
    float w = wval[p];
    const float4* r = (const float4*)((j < N_LIVE) ? (lx + (size_t)j * D)
                                                   : (nx + (size_t)(j - N_LIVE) * D));
    float4 v = r[lane];
    a0.x = fmaf(w, v.x, a0.x); a0.y = fmaf(w, v.y, a0.y);
    a0.z = fmaf(w, v.z, a0.z); a0.w = fmaf(w, v.w, a0.w);
  }
  a0.x += a1.x; a0.y += a1.y; a0.z += a1.z; a0.w += a1.w;
  part[nw][lane] = a0;
  __syncthreads();
  if (nw == 0) {
    float4 q0 = part[0][lane], q1 = part[1][lane], q2 = part[2][lane], q3 = part[3][lane];
    float4 r;
    r.x = ((q0.x + q1.x) + (q2.x + q3.x)) * inv;
    r.y = ((q0.y + q1.y) + (q2.y + q3.y)) * inv;
    r.z = ((q0.z + q1.z) + (q2.z + q3.z)) * inv;
    r.w = ((q0.w + q1.w) + (q2.w + q3.w)) * inv;
    ((float4*)(boot + ((size_t)b * NROW + n) * D))[lane] = r;
  }
}

// ---------------- kernel 4: std over bootstrap rows + epilogue ----------------
// 1024 threads: 4 row-stripes of 25 -> 4x fewer serial strided loads than the
// 256-thread version. Two-pass std preserved (no sumsq cancellation risk).
__global__ __launch_bounds__(1024) void k_final(
    const float* __restrict__ boot, const float* __restrict__ xt,
    const float* __restrict__ ts_p, float* __restrict__ out) {
  int b = blockIdx.x;
  int tid = threadIdx.x;
  int d = tid & 255;
  int st = tid >> 8;                 // stripe 0..3: rows st, st+4, ...
  float ts = *ts_p;
  const float* bb = boot + (size_t)b * NROW * D + d;
  __shared__ float red[4][256];
  __shared__ float mrow[256];
  __shared__ int wok[4];
  float s = 0.f;
#pragma unroll 5
  for (int i = 0; i < 25; i++) s += bb[(size_t)(st + 4 * i) * D];
  red[st][d] = s;
  __syncthreads();
  if (st == 0) mrow[d] = (red[0][d] + red[1][d] + red[2][d] + red[3][d]) / (float)NS;
  __syncthreads();
  float mean = mrow[d];
  float vs = 0.f;
#pragma unroll 5
  for (int i = 0; i < 25; i++) {
    float t = bb[(size_t)(st + 4 * i) * D] - mean;
    vs += t * t;
  }
  red[st][d] = vs;
  __syncthreads();
  if (st == 0) {                     // waves 0..3 entirely inside (tid<256)
    float var = (red[0][d] + red[1][d] + red[2][d] + red[3][d]) / (float)(NS - 1);
    float sigma_raw = sqrtf(var);
    // std((x - xt)/ts) = std(x)/ts (ts>0); condition: sigma_v < EPS*ts
    bool ok = (sigma_raw / ts) < (EPS * ts);
    // score = (sum_k w*x - xt)/ts  since sum_k w == 1
    out[(size_t)b * D + d] = (bb[(size_t)NS * D] - xt[(size_t)b * D + d]) / ts;
    unsigned long long m = __ballot(ok);
    if ((d & 63) == 0) wok[d >> 6] = (m == 0xFFFFFFFFFFFFFFFFull) ? 1 : 0;
  }
  __syncthreads();
  if (tid == 0)
    out[(size_t)B * D + b] = (wok[0] & wok[1] & wok[2] & wok[3]) ? 1.0f : 0.0f;
}

extern "C" void kernel_launch(void* const* d_in, const int* in_sizes, int n_in,
                              void* d_out, int out_size, void* d_ws, size_t ws_size,
                              hipStream_t stream) {
  const float* xt       = (const float*)d_in[0];
  const float* live_x0  = (const float*)d_in[1];
  const float* live_ll  = (const float*)d_in[2];
  const float* x0n      = (const float*)d_in[3];
  const float* lln      = (const float*)d_in[4];
  const float* ts_p     = (const float*)d_in[5];
  const int*   boot_idx = (const int*)d_in[6];
  float* out = (float*)d_out;
  float* ws  = (float*)d_ws;

  unsigned* hdr            = (unsigned*)(ws + WS_HDR);
  float* bmax              = ws + WS_BMAX;
  float* logits            = ws + WS_LOGITS;
  float* act_e             = ws + WS_ACTE;
  int*   act_idx           = (int*)(ws + WS_ACTI);
  unsigned short* lut      = (unsigned short*)(ws + WS_LUT);
  float* boot              = ws + WS_BOOT;

  k_logits<<<dim3(LBLK, B), 256, 0, stream>>>(xt, live_x0, live_ll, x0n, lln, ts_p, logits, bmax, hdr);
  k_select<<<dim3(8, B), 256, 0, stream>>>(logits, bmax, hdr, act_e, act_idx, lut);
  k_boot<<<dim3(NROW, B), 256, 0, stream>>>(live_x0, x0n, act_e, act_idx, hdr, lut, boot_idx, boot);
  k_final<<<dim3(B), 1024, 0, stream>>>(boot, xt, ts_p, out);
}

// Round 9
// 171.146 us; speedup vs baseline: 1.1196x; 1.0030x over previous
//
#include <hip/hip_runtime.h>
#include <math.h>

#define B 8
#define D 256
#define N_LIVE 10000
#define K_NEW 32
#define KC 10032
#define NS 100
#define NROW 101            // 100 bootstrap rows + 1 plain-softmax row (the score)
#define EPS 0.1f
#define CAP 1024            // active-set capacity (expected ~75 per b)
#define ACT_CUT 87.0f       // exp(-87)=1.65e-38: below fp32-normal -> weight 0 anyway
#define LBLK 314            // k_logits blocks per b (32 particles each; last partial)
#define BMAX_STRIDE 320

// ---- workspace layout in floats ----
// hdr: act_cnt[8] at [128..135] (slots 0..127 unused, kept for layout stability)
#define WS_HDR    0                            // 160 ints
#define WS_BMAX   160                          // B*320 floats: per-block maxima
#define WS_LOGITS (WS_BMAX + B * BMAX_STRIDE)  // B*KC floats
#define WS_ACTE   (WS_LOGITS + B * KC)         // B*CAP floats: e_j = exp(l-M)
#define WS_ACTI   (WS_ACTE + B * CAP)          // B*CAP ints: particle index j
#define WS_LUT    (WS_ACTI + B * CAP)          // B*KC ushorts = B*KC/2 floats
#define WS_BOOT   (WS_LUT + B * KC / 2)        // B*NROW*D floats   (~1.4 MB total)

// NOTE (r8 lesson): hipLaunchCooperativeKernel does NOT work in this harness
// (graph-capture path rejects it; output stayed poisoned). Keep discrete
// dispatches with stream-order dependencies.

// ---------------- kernel 1: logits[b,k] + per-block max ----------------
// 8 particles per wave (32/block): 8 independent 1KB row loads in flight,
// 8 interleaved shuffle-reduce chains. No global atomics (r4 lesson: 20k
// atomicMax onto 8 lines serialized ~50us). Block (0,b) also zeroes the
// act_cnt counter (replaces the hipMemsetAsync dispatch).
__global__ __launch_bounds__(256) void k_logits(
    const float* __restrict__ xt, const float* __restrict__ live_x0,
    const float* __restrict__ live_ll, const float* __restrict__ x0n,
    const float* __restrict__ lln, const float* __restrict__ ts_p,
    float* __restrict__ logits, float* __restrict__ bmax,
    unsigned* __restrict__ hdr) {
  int b = blockIdx.y;
  if (blockIdx.x == 0 && threadIdx.x == 0) hdr[128 + b] = 0;  // act_cnt := 0
  int w = threadIdx.x >> 6;
  int lane = threadIdx.x & 63;
  int k0 = blockIdx.x * 32 + w * 8;
  bool valid = (k0 < KC);
  int kb = valid ? k0 : 0;                 // safe dup loads for the dead waves
  float4 c = ((const float4*)(xt + b * D))[lane];

  float s[8];
#pragma unroll
  for (int p = 0; p < 8; p++) {
    int k = kb + p;
    const float* src = (k < N_LIVE)
        ? (live_x0 + ((size_t)b * N_LIVE + k) * D)
        : (x0n + ((size_t)b * K_NEW + (k - N_LIVE)) * D);
    float4 v = ((const float4*)src)[lane];
    float dx = v.x - c.x, dy = v.y - c.y, dz = v.z - c.z, dw = v.w - c.w;
    s[p] = dx * dx + dy * dy + dz * dz + dw * dw;
  }
#pragma unroll
  for (int off = 32; off; off >>= 1) {     // 8 interleaved chains hide DS latency
#pragma unroll
    for (int p = 0; p < 8; p++) s[p] += __shfl_xor(s[p], off);
  }
  __shared__ float wlog[4];
  if (lane == 0) {
    float ts = *ts_p;
    float inv2 = 0.5f / (ts * ts), lts = logf(ts);
    float o[8];
#pragma unroll
    for (int p = 0; p < 8; p++) {
      int k = kb + p;
      o[p] = (k < N_LIVE)
          ? live_ll[(size_t)b * N_LIVE + k] - s[p] * inv2 - lts
          : lln[(size_t)b * K_NEW + (k - N_LIVE)];   // gaussian corr cancels exactly
    }
    if (valid) {
      float4 o0 = {o[0], o[1], o[2], o[3]}, o1 = {o[4], o[5], o[6], o[7]};
      *(float4*)(logits + (size_t)b * KC + kb) = o0;
      *(float4*)(logits + (size_t)b * KC + kb + 4) = o1;
      wlog[w] = fmaxf(fmaxf(fmaxf(o[0], o[1]), fmaxf(o[2], o[3])),
                      fmaxf(fmaxf(o[4], o[5]), fmaxf(o[6], o[7])));
    } else {
      wlog[w] = -INFINITY;
    }
  }
  __syncthreads();
  if (threadIdx.x == 0)
    bmax[b * BMAX_STRIDE + blockIdx.x] =
        fmaxf(fmaxf(wlog[0], wlog[1]), fmaxf(wlog[2], wlog[3]));
}

// ---------------- kernel 2: max-reduce + active-set selection (fused) ----------------
// 8 blocks per b; each block redundantly reduces the 314 per-block maxima
// (trivial) then selects. Active = logit within ACT_CUT of the per-b max;
// everything else has exp(l-M) below fp32-normal range -> weight 0 in fp32.
__global__ __launch_bounds__(256) void k_select(
    const float* __restrict__ logits, const float* __restrict__ bmax,
    unsigned* __restrict__ hdr, float* __restrict__ act_e,
    int* __restrict__ act_idx, unsigned short* __restrict__ lut) {
  int b = blockIdx.y;
  __shared__ float sm[4];
  float m = -INFINITY;
  for (int i = threadIdx.x; i < LBLK; i += 256)
    m = fmaxf(m, bmax[b * BMAX_STRIDE + i]);
#pragma unroll
  for (int off = 32; off; off >>= 1) m = fmaxf(m, __shfl_xor(m, off));
  if ((threadIdx.x & 63) == 0) sm[threadIdx.x >> 6] = m;
  __syncthreads();
  float M = fmaxf(fmaxf(sm[0], sm[1]), fmaxf(sm[2], sm[3]));

  int tid = blockIdx.x * 256 + threadIdx.x;
  const float* lg = logits + (size_t)b * KC;
  int* cnt = (int*)&hdr[128 + b];
  for (int k = tid; k < KC; k += 8 * 256) {
    float l = lg[k];
    unsigned short v = 0;
    if (l > M - ACT_CUT) {
      int pos = atomicAdd(cnt, 1);            // rare: ~75 per b total
      if (pos < CAP) {
        act_e[b * CAP + pos] = expf(l - M);
        act_idx[b * CAP + pos] = k;
        v = (unsigned short)(pos + 1);
      }
    }
    lut[(size_t)b * KC + k] = v;
  }
}

// ---------------- kernel 3: fused count + sparse weighted sum ----------------
// One block per (n,b). The 20KB uint16 lut is staged into LDS so the 10032
// random lookups per block are ds_read_u16 (2-way conflicts free) instead of
// L1 line-serialized gathers. LDS atomics only on ~75 hits. Weighted sum:
// lane covers d via float4 (64 lanes x 16B = full row), 4 waves split the
// nnz rows 4-ways with 2-way unroll, LDS partial-combine at the end.
// n==100 is the identity row (plain softmax -> final score).
__global__ __launch_bounds__(256) void k_boot(
    const float* __restrict__ live_x0, const float* __restrict__ x0n,
    const float* __restrict__ act_e, const int* __restrict__ act_idx,
    const unsigned* __restrict__ hdr, const unsigned short* __restrict__ lut,
    const int* __restrict__ boot_idx, float* __restrict__ boot) {
  int n = blockIdx.x;   // 0..100
  int b = blockIdx.y;
  int tid = threadIdx.x;
  int nw = tid >> 6, lane = tid & 63;
  __shared__ unsigned short slut[KC];   // 20064 B
  __shared__ int cnt[CAP];
  __shared__ float wval[CAP];
  __shared__ int widx[CAP];
  __shared__ float4 part[4][64];
  __shared__ int snnz;
  __shared__ float sden[4];
  int A = min((int)hdr[128 + b], CAP);
  for (int i = tid; i < A; i += 256) cnt[i] = 0;
  if (tid == 0) snnz = 0;
  if (n < NS) {                         // stage lut -> LDS (coalesced u32 copy)
    const unsigned* src = (const unsigned*)(lut + (size_t)b * KC);
    unsigned* dst = (unsigned*)slut;
    for (int i = tid; i < KC / 2; i += 256) dst[i] = src[i];
  }
  __syncthreads();

  if (n < NS) {
    const int4* row = (const int4*)(boot_idx + ((size_t)n * B + b) * KC);
    for (int k = tid; k < KC / 4; k += 256) {   // KC%4==0
      int4 v = row[k];
      int t;
      t = slut[v.x]; if (t) atomicAdd(&cnt[t - 1], 1);
      t = slut[v.y]; if (t) atomicAdd(&cnt[t - 1], 1);
      t = slut[v.z]; if (t) atomicAdd(&cnt[t - 1], 1);
      t = slut[v.w]; if (t) atomicAdd(&cnt[t - 1], 1);
    }
  } else {
    for (int i = tid; i < A; i += 256) cnt[i] = 1;
  }
  __syncthreads();

  // compact nonzero actives + denominator
  float dpart = 0.f;
  for (int i = tid; i < A; i += 256) {
    int c = cnt[i];
    if (c) {
      float w = (float)c * act_e[b * CAP + i];
      int pos = atomicAdd(&snnz, 1);
      wval[pos] = w;
      widx[pos] = act_idx[b * CAP + i];
      dpart += w;
    }
  }
#pragma unroll
  for (int off = 32; off; off >>= 1) dpart += __shfl_xor(dpart, off);
  if ((tid & 63) == 0) sden[tid >> 6] = dpart;
  __syncthreads();
  float inv = 1.f / (sden[0] + sden[1] + sden[2] + sden[3]);
  int nnz = snnz;

  const float* lx = live_x0 + (size_t)b * N_LIVE * D;
  const float* nx = x0n + (size_t)b * K_NEW * D;
  float4 a0 = {0.f, 0.f, 0.f, 0.f}, a1 = {0.f, 0.f, 0.f, 0.f};
  int p = nw;
  for (; p + 4 < nnz; p += 8) {          // 2 independent rows in flight per wave
    int j0 = widx[p], j1 = widx[p + 4];
    float w0 = wval[p], w1 = wval[p + 4];
    const float4* r0 = (const float4*)((j0 < N_LIVE) ? (lx + (size_t)j0 * D)
                                                     : (nx + (size_t)(j0 - N_LIVE) * D));
    const float4* r1 = (const float4*)((j1 < N_LIVE) ? (lx + (size_t)j1 * D)
                                                     : (nx + (size_t)(j1 - N_LIVE) * D));
    float4 v0 = r0[lane], v1 = r1[lane];
    a0.x = fmaf(w0, v0.x, a0.x); a0.y = fmaf(w0, v0.y, a0.y);
    a0.z = fmaf(w0, v0.z, a0.z); a0.w = fmaf(w0, v0.w, a0.w);
    a1.x = fmaf(w1, v1.x, a1.x); a1.y = fmaf(w1, v1.y, a1.y);
    a1.z = fmaf(w1, v1.z, a1.z); a1.w = fmaf(w1, v1.w, a1.w);
  }
  if (p < nnz) {
    int j = widx[p];
    float w = wval[p];
    const float4* r = (const float4*)((j < N_LIVE) ? (lx + (size_t)j * D)
                                                   : (nx + (size_t)(j - N_LIVE) * D));
    float4 v = r[lane];
    a0.x = fmaf(w, v.x, a0.x); a0.y = fmaf(w, v.y, a0.y);
    a0.z = fmaf(w, v.z, a0.z); a0.w = fmaf(w, v.w, a0.w);
  }
  a0.x += a1.x; a0.y += a1.y; a0.z += a1.z; a0.w += a1.w;
  part[nw][lane] = a0;
  __syncthreads();
  if (nw == 0) {
    float4 q0 = part[0][lane], q1 = part[1][lane], q2 = part[2][lane], q3 = part[3][lane];
    float4 r;
    r.x = ((q0.x + q1.x) + (q2.x + q3.x)) * inv;
    r.y = ((q0.y + q1.y) + (q2.y + q3.y)) * inv;
    r.z = ((q0.z + q1.z) + (q2.z + q3.z)) * inv;
    r.w = ((q0.w + q1.w) + (q2.w + q3.w)) * inv;
    ((float4*)(boot + ((size_t)b * NROW + n) * D))[lane] = r;
  }
}

// ---------------- kernel 4: std over bootstrap rows + epilogue ----------------
// 1024 threads: 4 row-stripes of 25 -> 4x fewer serial strided loads than the
// 256-thread version. Two-pass std preserved (no sumsq cancellation risk).
__global__ __launch_bounds__(1024) void k_final(
    const float* __restrict__ boot, const float* __restrict__ xt,
    const float* __restrict__ ts_p, float* __restrict__ out) {
  int b = blockIdx.x;
  int tid = threadIdx.x;
  int d = tid & 255;
  int st = tid >> 8;                 // stripe 0..3: rows st, st+4, ...
  float ts = *ts_p;
  const float* bb = boot + (size_t)b * NROW * D + d;
  __shared__ float red[4][256];
  __shared__ float mrow[256];
  __shared__ int wok[4];
  float s = 0.f;
#pragma unroll 5
  for (int i = 0; i < 25; i++) s += bb[(size_t)(st + 4 * i) * D];
  red[st][d] = s;
  __syncthreads();
  if (st == 0) mrow[d] = (red[0][d] + red[1][d] + red[2][d] + red[3][d]) / (float)NS;
  __syncthreads();
  float mean = mrow[d];
  float vs = 0.f;
#pragma unroll 5
  for (int i = 0; i < 25; i++) {
    float t = bb[(size_t)(st + 4 * i) * D] - mean;
    vs += t * t;
  }
  red[st][d] = vs;
  __syncthreads();
  if (st == 0) {                     // waves 0..3 entirely inside (tid<256)
    float var = (red[0][d] + red[1][d] + red[2][d] + red[3][d]) / (float)(NS - 1);
    float sigma_raw = sqrtf(var);
    // std((x - xt)/ts) = std(x)/ts (ts>0); condition: sigma_v < EPS*ts
    bool ok = (sigma_raw / ts) < (EPS * ts);
    // score = (sum_k w*x - xt)/ts  since sum_k w == 1
    out[(size_t)b * D + d] = (bb[(size_t)NS * D] - xt[(size_t)b * D + d]) / ts;
    unsigned long long m = __ballot(ok);
    if ((d & 63) == 0) wok[d >> 6] = (m == 0xFFFFFFFFFFFFFFFFull) ? 1 : 0;
  }
  __syncthreads();
  if (tid == 0)
    out[(size_t)B * D + b] = (wok[0] & wok[1] & wok[2] & wok[3]) ? 1.0f : 0.0f;
}

extern "C" void kernel_launch(void* const* d_in, const int* in_sizes, int n_in,
                              void* d_out, int out_size, void* d_ws, size_t ws_size,
                              hipStream_t stream) {
  const float* xt       = (const float*)d_in[0];
  const float* live_x0  = (const float*)d_in[1];
  const float* live_ll  = (const float*)d_in[2];
  const float* x0n      = (const float*)d_in[3];
  const float* lln      = (const float*)d_in[4];
  const float* ts_p     = (const float*)d_in[5];
  const int*   boot_idx = (const int*)d_in[6];
  float* out = (float*)d_out;
  float* ws  = (float*)d_ws;

  unsigned* hdr            = (unsigned*)(ws + WS_HDR);
  float* bmax              = ws + WS_BMAX;
  float* logits            = ws + WS_LOGITS;
  float* act_e             = ws + WS_ACTE;
  int*   act_idx           = (int*)(ws + WS_ACTI);
  unsigned short* lut      = (unsigned short*)(ws + WS_LUT);
  float* boot              = ws + WS_BOOT;

  k_logits<<<dim3(LBLK, B), 256, 0, stream>>>(xt, live_x0, live_ll, x0n, lln, ts_p, logits, bmax, hdr);
  k_select<<<dim3(8, B), 256, 0, stream>>>(logits, bmax, hdr, act_e, act_idx, lut);
  k_boot<<<dim3(NROW, B), 256, 0, stream>>>(live_x0, x0n, act_e, act_idx, hdr, lut, boot_idx, boot);
  k_final<<<dim3(B), 1024, 0, stream>>>(boot, xt, ts_p, out);
}